// Round 3
// baseline (143.782 us; speedup 1.0000x reference)
//
#include <hip/hip_runtime.h>
#include <hip/hip_bf16.h>

// Problem constants (fixed by reference): N=4096, D=256, T=0.5, EPS=1e-8
#define PN   4096
#define PN2  8192
#define PD   256
#define TILE 128
#define NBLK (PN2 / TILE)             // 64 tile-blocks per dim
#define NTRI (NBLK * (NBLK + 1) / 2)  // 2080 upper-tri blocks

typedef __attribute__((ext_vector_type(8))) short bf16x8;   // 8 bf16 = 4 VGPRs
typedef __attribute__((ext_vector_type(4))) float f32x4;

// ---------------------------------------------------------------------------
// Kernel 1: row-normalize z = [z_i; z_j] (fp32), write bf16 zn, zero rowsum
// ---------------------------------------------------------------------------
__global__ __launch_bounds__(256) void normalize_kernel(
    const float* __restrict__ zi, const float* __restrict__ zj,
    __hip_bfloat16* __restrict__ zn, float* __restrict__ rowsum) {
  int r = blockIdx.x;          // 0..8191
  int tid = threadIdx.x;       // 0..255 == D
  const float* src = (r < PN) ? (zi + (size_t)r * PD) : (zj + (size_t)(r - PN) * PD);
  float x = src[tid];
  float s = x * x;
  #pragma unroll
  for (int off = 32; off >= 1; off >>= 1) s += __shfl_xor(s, off, 64);
  __shared__ float p[4];
  if ((tid & 63) == 0) p[tid >> 6] = s;
  __syncthreads();
  float tot = p[0] + p[1] + p[2] + p[3];
  float nrm = fmaxf(sqrtf(tot), 1e-8f);
  zn[(size_t)r * PD + tid] = __float2bfloat16(x / nrm);
  if (tid == 0) rowsum[r] = 0.0f;   // ws is re-poisoned 0xAA before every launch
}

// ---------------------------------------------------------------------------
// Kernel 2: sim = zn @ zn^T, upper-triangular blocks, NO LDS STAGING.
// For mfma_f32_16x16x32_bf16 the A and B operand fragments have identical
// lane layouts over row-major zn (row = lane&15, k = quad*8+j), so both
// operands load directly from global — no transpose, no barriers, no ds_read.
// Off-diag block (bi<bj): exp-tile reduced along BOTH axes (symmetry).
// Diag block: full tile, row-reduce only, diagonal masked.
// ---------------------------------------------------------------------------
__global__ __launch_bounds__(256) void simsum_kernel(
    const __hip_bfloat16* __restrict__ zn,
    float* __restrict__ rowsum, float* __restrict__ pos) {
  // Decode upper-tri (bi<=bj) from linear index: T(bj)=bj(bj+1)/2
  const int idx = blockIdx.x;
  int bj = (int)((sqrtf(8.0f * (float)idx + 1.0f) - 1.0f) * 0.5f);
  while ((bj + 1) * (bj + 2) / 2 <= idx) ++bj;
  while (bj * (bj + 1) / 2 > idx) --bj;
  const int bi = idx - bj * (bj + 1) / 2;
  const bool diagBlk = (bi == bj);
  const bool posBlk  = (bj == bi + PN / TILE);   // cols == rows + 4096

  const int tid  = threadIdx.x;
  const int wave = tid >> 6;
  const int lane = tid & 63;
  const int quad = lane >> 4;
  const int c16  = lane & 15;
  const int wrow = bi * TILE + (wave >> 1) * 64;   // wave's 64-row slab
  const int wcol = bj * TILE + (wave & 1) * 64;    // wave's 64-col slab

  // Per-lane row pointers for the 4 A-row groups and 4 B-row groups.
  const __hip_bfloat16* aP[4];
  const __hip_bfloat16* bP[4];
  #pragma unroll
  for (int i = 0; i < 4; ++i) {
    aP[i] = zn + (size_t)(wrow + i * 16 + c16) * PD + quad * 8;
    bP[i] = zn + (size_t)(wcol + i * 16 + c16) * PD + quad * 8;
  }

  f32x4 acc[4][4];
  #pragma unroll
  for (int i = 0; i < 4; ++i)
    #pragma unroll
    for (int j = 0; j < 4; ++j)
      acc[i][j] = (f32x4){0.f, 0.f, 0.f, 0.f};

  // K loop: 8 steps of K=32; offsets fit global_load offset immediates.
  #pragma unroll
  for (int k = 0; k < PD; k += 32) {
    bf16x8 a[4], b[4];
    #pragma unroll
    for (int mi = 0; mi < 4; ++mi) a[mi] = *(const bf16x8*)(aP[mi] + k);
    #pragma unroll
    for (int ni = 0; ni < 4; ++ni) b[ni] = *(const bf16x8*)(bP[ni] + k);
    #pragma unroll
    for (int mi = 0; mi < 4; ++mi)
      #pragma unroll
      for (int ni = 0; ni < 4; ++ni)
        acc[mi][ni] = __builtin_amdgcn_mfma_f32_16x16x32_bf16(a[mi], b[ni], acc[mi][ni], 0, 0, 0);
  }

  // Epilogue. C/D layout: col=lane&15, row=quad*4+reg  [measured m89/m91]
  float colsum[4] = {0.f, 0.f, 0.f, 0.f};
  #pragma unroll
  for (int mi = 0; mi < 4; ++mi) {
    int rbase = wrow + mi * 16 + quad * 4;
    float rs[4] = {0.f, 0.f, 0.f, 0.f};
    #pragma unroll
    for (int ni = 0; ni < 4; ++ni) {
      int gcol = wcol + ni * 16 + c16;
      #pragma unroll
      for (int t = 0; t < 4; ++t) {
        int grow = rbase + t;
        float sim = acc[mi][ni][t];
        float e = __expf(2.0f * sim);               // exp(sim / T), T=0.5
        if (diagBlk && gcol == grow) e = 0.0f;      // mask diagonal
        rs[t] += e;
        colsum[ni] += e;
        if (posBlk && gcol == grow + PN) {          // positive pair (and mirror)
          pos[grow] = sim;
          pos[grow + PN] = sim;
        }
      }
    }
    #pragma unroll
    for (int t = 0; t < 4; ++t) {
      #pragma unroll
      for (int off = 1; off <= 8; off <<= 1) rs[t] += __shfl_xor(rs[t], off, 64);
    }
    if (c16 == 0) {
      #pragma unroll
      for (int t = 0; t < 4; ++t) atomicAdd(&rowsum[rbase + t], rs[t]);
    }
  }
  if (!diagBlk) {   // column contributions = mirrored rows (symmetry)
    #pragma unroll
    for (int ni = 0; ni < 4; ++ni) {
      float cs = colsum[ni];
      cs += __shfl_xor(cs, 16, 64);
      cs += __shfl_xor(cs, 32, 64);
      if (quad == 0) atomicAdd(&rowsum[wcol + ni * 16 + c16], cs);
    }
  }
}

// ---------------------------------------------------------------------------
// Kernel 3: loss_i = log(denom_i) - 2*pos_i ; out = sum(w*loss)/sum(w)
// ---------------------------------------------------------------------------
__global__ __launch_bounds__(1024) void finalize_kernel(
    const float* __restrict__ rowsum, const float* __restrict__ pos,
    const float* __restrict__ w, float* __restrict__ out) {
  int tid = threadIdx.x;
  float wl = 0.f, ws = 0.f;
  for (int i = tid; i < PN2; i += 1024) {
    float li = logf(rowsum[i]) - 2.0f * pos[i];
    float wi = w[i & (PN - 1)];
    wl += wi * li;
    ws += wi;
  }
  #pragma unroll
  for (int off = 32; off >= 1; off >>= 1) {
    wl += __shfl_xor(wl, off, 64);
    ws += __shfl_xor(ws, off, 64);
  }
  __shared__ float pl[16], pw[16];
  if ((tid & 63) == 0) { pl[tid >> 6] = wl; pw[tid >> 6] = ws; }
  __syncthreads();
  if (tid == 0) {
    float sl = 0.f, sw = 0.f;
    #pragma unroll
    for (int k = 0; k < 16; ++k) { sl += pl[k]; sw += pw[k]; }
    out[0] = sl / sw;
  }
}

// ---------------------------------------------------------------------------
extern "C" void kernel_launch(void* const* d_in, const int* in_sizes, int n_in,
                              void* d_out, int out_size, void* d_ws, size_t ws_size,
                              hipStream_t stream) {
  const float* zi = (const float*)d_in[0];
  const float* zj = (const float*)d_in[1];
  const float* w  = (const float*)d_in[2];
  float* out = (float*)d_out;

  // Workspace: zn bf16 [8192*256] = 4 MiB, then rowsum f32[8192], pos f32[8192]
  __hip_bfloat16* zn = (__hip_bfloat16*)d_ws;
  float* rowsum = (float*)((char*)d_ws + (size_t)PN2 * PD * 2);
  float* pos = rowsum + PN2;

  normalize_kernel<<<PN2, 256, 0, stream>>>(zi, zj, zn, rowsum);
  simsum_kernel<<<NTRI, 256, 0, stream>>>(zn, rowsum, pos);
  finalize_kernel<<<1, 1024, 0, stream>>>(rowsum, pos, w, out);
}

// Round 4
// 112.391 us; speedup vs baseline: 1.2793x; 1.2793x over previous
//
#include <hip/hip_runtime.h>
#include <hip/hip_bf16.h>

// Problem constants (fixed by reference): N=4096, D=256, T=0.5, EPS=1e-8
#define PN   4096
#define PN2  8192
#define PD   256
#define TILE 128
#define NBLK (PN2 / TILE)             // 64 tile-blocks per dim
#define NTRI (NBLK * (NBLK + 1) / 2)  // 2080 upper-tri blocks

typedef __attribute__((ext_vector_type(8))) short bf16x8;   // 8 bf16 = 4 VGPRs
typedef __attribute__((ext_vector_type(4))) float f32x4;

// zn_perm layout: row r = g*16 + rr (g in [0,512)), k = c*32 + q*8 + j.
// element index P = (g*8 + c)*512 + q*128 + rr*8 + j
// => a wave's fragment for (row-group g, k-chunk c) is the contiguous 1 KB
//    block at (g*8+c)*512, read as lane*8..lane*8+7 (lane = q*16 + rr).
//    Matches mfma_f32_16x16x32_bf16 A/B operand layout (verified R3).

// ---------------------------------------------------------------------------
// Kernel 1: row-normalize z = [z_i; z_j], write PERMUTED bf16 zn, zero rowsum
// ---------------------------------------------------------------------------
__global__ __launch_bounds__(256) void normalize_kernel(
    const float* __restrict__ zi, const float* __restrict__ zj,
    __hip_bfloat16* __restrict__ zn, float* __restrict__ rowsum) {
  int r = blockIdx.x;          // 0..8191
  int tid = threadIdx.x;       // 0..255 == k
  const float* src = (r < PN) ? (zi + (size_t)r * PD) : (zj + (size_t)(r - PN) * PD);
  float x = src[tid];
  float s = x * x;
  #pragma unroll
  for (int off = 32; off >= 1; off >>= 1) s += __shfl_xor(s, off, 64);
  __shared__ float p[4];
  if ((tid & 63) == 0) p[tid >> 6] = s;
  __syncthreads();
  float tot = p[0] + p[1] + p[2] + p[3];
  float nrm = fmaxf(sqrtf(tot), 1e-8f);
  int g  = r >> 4, rr = r & 15;
  int c  = tid >> 5, q = (tid >> 3) & 3, j = tid & 7;
  zn[(size_t)(g * 8 + c) * 512 + q * 128 + rr * 8 + j] = __float2bfloat16(x / nrm);
  if (tid == 0) rowsum[r] = 0.0f;   // ws is re-poisoned 0xAA before every launch
}

// ---------------------------------------------------------------------------
// Kernel 2: sim = zn @ zn^T, upper-tri blocks, NO LDS, NO barriers.
// Fragment loads are contiguous 1 KB global_load_dwordx4 from zn_perm
// (L2-resident, 4 MB). Off-diag blocks reduce exp-tile along both axes.
// ---------------------------------------------------------------------------
__global__ __launch_bounds__(256) void simsum_kernel(
    const __hip_bfloat16* __restrict__ zn,
    float* __restrict__ rowsum, float* __restrict__ pos) {
  // Decode upper-tri (bi<=bj) from linear index: T(bj)=bj(bj+1)/2
  const int idx = blockIdx.x;
  int bj = (int)((sqrtf(8.0f * (float)idx + 1.0f) - 1.0f) * 0.5f);
  while ((bj + 1) * (bj + 2) / 2 <= idx) ++bj;
  while (bj * (bj + 1) / 2 > idx) --bj;
  const int bi = idx - bj * (bj + 1) / 2;
  const bool diagBlk = (bi == bj);
  const bool posBlk  = (bj == bi + PN / TILE);   // cols == rows + 4096

  const int tid  = threadIdx.x;
  const int wave = tid >> 6;
  const int lane = tid & 63;
  const int quad = lane >> 4;
  const int c16  = lane & 15;
  const int wrow = bi * TILE + (wave >> 1) * 64;   // wave's 64-row slab
  const int wcol = bj * TILE + (wave & 1) * 64;    // wave's 64-col slab

  // Fragment base pointers: row-group (wrow/16 + mi), this lane's 16 B slot.
  const __hip_bfloat16* aB[4];
  const __hip_bfloat16* bB[4];
  #pragma unroll
  for (int i = 0; i < 4; ++i) {
    aB[i] = zn + (size_t)((wrow >> 4) + i) * 4096 + lane * 8;
    bB[i] = zn + (size_t)((wcol >> 4) + i) * 4096 + lane * 8;
  }

  f32x4 acc[4][4];
  #pragma unroll
  for (int i = 0; i < 4; ++i)
    #pragma unroll
    for (int j = 0; j < 4; ++j)
      acc[i][j] = (f32x4){0.f, 0.f, 0.f, 0.f};

  // K loop: 8 chunks of K=32; chunk stride = 512 elems = 1024 B (offset imm ok)
  #pragma unroll
  for (int c = 0; c < 8; ++c) {
    bf16x8 a[4], b[4];
    #pragma unroll
    for (int mi = 0; mi < 4; ++mi) a[mi] = *(const bf16x8*)(aB[mi] + c * 512);
    #pragma unroll
    for (int ni = 0; ni < 4; ++ni) b[ni] = *(const bf16x8*)(bB[ni] + c * 512);
    #pragma unroll
    for (int mi = 0; mi < 4; ++mi)
      #pragma unroll
      for (int ni = 0; ni < 4; ++ni)
        acc[mi][ni] = __builtin_amdgcn_mfma_f32_16x16x32_bf16(a[mi], b[ni], acc[mi][ni], 0, 0, 0);
  }

  // Epilogue. C/D layout: col=lane&15, row=quad*4+reg  [measured m89/m91]
  float colsum[4] = {0.f, 0.f, 0.f, 0.f};
  #pragma unroll
  for (int mi = 0; mi < 4; ++mi) {
    int rbase = wrow + mi * 16 + quad * 4;
    float rs[4] = {0.f, 0.f, 0.f, 0.f};
    #pragma unroll
    for (int ni = 0; ni < 4; ++ni) {
      int gcol = wcol + ni * 16 + c16;
      #pragma unroll
      for (int t = 0; t < 4; ++t) {
        int grow = rbase + t;
        float sim = acc[mi][ni][t];
        float e = __expf(2.0f * sim);               // exp(sim / T), T=0.5
        if (diagBlk && gcol == grow) e = 0.0f;      // mask diagonal
        rs[t] += e;
        colsum[ni] += e;
        if (posBlk && gcol == grow + PN) {          // positive pair (and mirror)
          pos[grow] = sim;
          pos[grow + PN] = sim;
        }
      }
    }
    #pragma unroll
    for (int t = 0; t < 4; ++t) {
      #pragma unroll
      for (int off = 1; off <= 8; off <<= 1) rs[t] += __shfl_xor(rs[t], off, 64);
    }
    if (c16 == 0) {
      #pragma unroll
      for (int t = 0; t < 4; ++t) atomicAdd(&rowsum[rbase + t], rs[t]);
    }
  }
  if (!diagBlk) {   // column contributions = mirrored rows (symmetry)
    #pragma unroll
    for (int ni = 0; ni < 4; ++ni) {
      float cs = colsum[ni];
      cs += __shfl_xor(cs, 16, 64);
      cs += __shfl_xor(cs, 32, 64);
      if (quad == 0) atomicAdd(&rowsum[wcol + ni * 16 + c16], cs);
    }
  }
}

// ---------------------------------------------------------------------------
// Kernel 3: loss_i = log(denom_i) - 2*pos_i ; out = sum(w*loss)/sum(w)
// ---------------------------------------------------------------------------
__global__ __launch_bounds__(1024) void finalize_kernel(
    const float* __restrict__ rowsum, const float* __restrict__ pos,
    const float* __restrict__ w, float* __restrict__ out) {
  int tid = threadIdx.x;
  float wl = 0.f, ws = 0.f;
  for (int i = tid; i < PN2; i += 1024) {
    float li = logf(rowsum[i]) - 2.0f * pos[i];
    float wi = w[i & (PN - 1)];
    wl += wi * li;
    ws += wi;
  }
  #pragma unroll
  for (int off = 32; off >= 1; off >>= 1) {
    wl += __shfl_xor(wl, off, 64);
    ws += __shfl_xor(ws, off, 64);
  }
  __shared__ float pl[16], pw[16];
  if ((tid & 63) == 0) { pl[tid >> 6] = wl; pw[tid >> 6] = ws; }
  __syncthreads();
  if (tid == 0) {
    float sl = 0.f, sw = 0.f;
    #pragma unroll
    for (int k = 0; k < 16; ++k) { sl += pl[k]; sw += pw[k]; }
    out[0] = sl / sw;
  }
}

// ---------------------------------------------------------------------------
extern "C" void kernel_launch(void* const* d_in, const int* in_sizes, int n_in,
                              void* d_out, int out_size, void* d_ws, size_t ws_size,
                              hipStream_t stream) {
  const float* zi = (const float*)d_in[0];
  const float* zj = (const float*)d_in[1];
  const float* w  = (const float*)d_in[2];
  float* out = (float*)d_out;

  // Workspace: zn_perm bf16 [8192*256] = 4 MiB, then rowsum f32[8192], pos f32[8192]
  __hip_bfloat16* zn = (__hip_bfloat16*)d_ws;
  float* rowsum = (float*)((char*)d_ws + (size_t)PN2 * PD * 2);
  float* pos = rowsum + PN2;

  normalize_kernel<<<PN2, 256, 0, stream>>>(zi, zj, zn, rowsum);
  simsum_kernel<<<NTRI, 256, 0, stream>>>(zn, rowsum, pos);
  finalize_kernel<<<1, 1024, 0, stream>>>(rowsum, pos, w, out);
}

// Round 5
// 109.439 us; speedup vs baseline: 1.3138x; 1.0270x over previous
//
#include <hip/hip_runtime.h>
#include <hip/hip_bf16.h>

// Problem constants (fixed by reference): N=4096, D=256, T=0.5, EPS=1e-8
#define PN   4096
#define PN2  8192
#define PD   256
#define TILE 128
#define NBLK (PN2 / TILE)             // 64 tile-blocks per dim
#define NTRI (NBLK * (NBLK + 1) / 2)  // 2080 upper-tri blocks

typedef __attribute__((ext_vector_type(8))) short bf16x8;   // 8 bf16 = 4 VGPRs
typedef __attribute__((ext_vector_type(4))) float f32x4;

typedef const __attribute__((address_space(1))) void* gas_ptr;
typedef __attribute__((address_space(3))) void* las_ptr;

// zn_perm layout: row r = g*16 + rr (g in [0,512)), k = c*32 + q*8 + j.
// element index P = (g*8 + c)*512 + q*128 + rr*8 + j
// => fragment (row-group g, k-chunk c) = contiguous 1 KB at byte (g*8+c)*1024,
//    read as lane*16 (lane = q*16 + rr). Matches mfma_16x16x32_bf16 A/B operand
//    layout (verified R3/R4). A 128-row slab = 64 KB CONTIGUOUS (8 groups x 8 KB).

// ---------------------------------------------------------------------------
// Kernel 1: row-normalize z = [z_i; z_j], write PERMUTED bf16 zn, zero rowsum
// ---------------------------------------------------------------------------
__global__ __launch_bounds__(256) void normalize_kernel(
    const float* __restrict__ zi, const float* __restrict__ zj,
    __hip_bfloat16* __restrict__ zn, float* __restrict__ rowsum) {
  int r = blockIdx.x;          // 0..8191
  int tid = threadIdx.x;       // 0..255 == k
  const float* src = (r < PN) ? (zi + (size_t)r * PD) : (zj + (size_t)(r - PN) * PD);
  float x = src[tid];
  float s = x * x;
  #pragma unroll
  for (int off = 32; off >= 1; off >>= 1) s += __shfl_xor(s, off, 64);
  __shared__ float p[4];
  if ((tid & 63) == 0) p[tid >> 6] = s;
  __syncthreads();
  float tot = p[0] + p[1] + p[2] + p[3];
  float nrm = fmaxf(sqrtf(tot), 1e-8f);
  int g  = r >> 4, rr = r & 15;
  int c  = tid >> 5, q = (tid >> 3) & 3, j = tid & 7;
  zn[(size_t)(g * 8 + c) * 512 + q * 128 + rr * 8 + j] = __float2bfloat16(x / nrm);
  if (tid == 0) rowsum[r] = 0.0f;   // ws is re-poisoned 0xAA before every launch
}

// ---------------------------------------------------------------------------
// Kernel 2: sim = zn @ zn^T, upper-tri blocks. A-slab (64 KB, full K) staged
// to LDS ONCE per block (single barrier); B fragments direct from global
// (coalesced 1 KB dwordx4, no barrier dependence). 2 blocks/CU co-resident:
// one stages while the other computes. Off-diag blocks reduce both axes.
// ---------------------------------------------------------------------------
__global__ __launch_bounds__(256, 2) void simsum_kernel(
    const __hip_bfloat16* __restrict__ zn,
    float* __restrict__ rowsum, float* __restrict__ pos) {
  __shared__ char As[64 * 1024];   // A slab in zn_perm order: 8 groups x 8 KB

  // Decode upper-tri (bi<=bj) from linear index: T(bj)=bj(bj+1)/2
  const int idx = blockIdx.x;
  int bj = (int)((sqrtf(8.0f * (float)idx + 1.0f) - 1.0f) * 0.5f);
  while ((bj + 1) * (bj + 2) / 2 <= idx) ++bj;
  while (bj * (bj + 1) / 2 > idx) --bj;
  const int bi = idx - bj * (bj + 1) / 2;
  const bool diagBlk = (bi == bj);
  const bool posBlk  = (bj == bi + PN / TILE);   // cols == rows + 4096

  const int tid  = threadIdx.x;
  const int wave = tid >> 6;
  const int lane = tid & 63;
  const int quad = lane >> 4;
  const int c16  = lane & 15;
  const int wrow = bi * TILE + (wave >> 1) * 64;   // wave's 64-row slab
  const int wcol = bj * TILE + (wave & 1) * 64;    // wave's 64-col slab

  // Stage A slab: 64 KB contiguous from zn_perm, 16 wave-issues of 1 KB/wave.
  const char* aslab = (const char*)zn + (size_t)bi * 65536;
  #pragma unroll
  for (int p = 0; p < 16; ++p) {
    int off = (p * 4 + wave) * 1024;   // wave-uniform LDS base
    __builtin_amdgcn_global_load_lds((gas_ptr)(aslab + off + lane * 16),
                                     (las_ptr)(As + off), 16, 0, 0);
  }

  // B fragment base pointers (global, zn_perm order): group = bj*8+(wave&1)*4+ni
  const __hip_bfloat16* bB[4];
  #pragma unroll
  for (int i = 0; i < 4; ++i)
    bB[i] = zn + (size_t)(bj * 8 + (wave & 1) * 4 + i) * 4096 + lane * 8;

  f32x4 acc[4][4];
  #pragma unroll
  for (int i = 0; i < 4; ++i)
    #pragma unroll
    for (int j = 0; j < 4; ++j)
      acc[i][j] = (f32x4){0.f, 0.f, 0.f, 0.f};

  const int arowg = (wave >> 1) * 4;   // wave's first A group in the slab

  __syncthreads();   // the ONLY barrier: A slab visible

  #pragma unroll
  for (int c = 0; c < 8; ++c) {        // 8 chunks of K=32
    bf16x8 a[4], b[4];
    #pragma unroll
    for (int ni = 0; ni < 4; ++ni) b[ni] = *(const bf16x8*)(bB[ni] + c * 512);
    #pragma unroll
    for (int mi = 0; mi < 4; ++mi)
      a[mi] = *(const bf16x8*)(As + ((arowg + mi) * 8 + c) * 1024 + lane * 16);
    #pragma unroll
    for (int mi = 0; mi < 4; ++mi)
      #pragma unroll
      for (int ni = 0; ni < 4; ++ni)
        acc[mi][ni] = __builtin_amdgcn_mfma_f32_16x16x32_bf16(a[mi], b[ni], acc[mi][ni], 0, 0, 0);
  }

  // Epilogue. C/D layout: col=lane&15, row=quad*4+reg  [measured m89/m91]
  float colsum[4] = {0.f, 0.f, 0.f, 0.f};
  #pragma unroll
  for (int mi = 0; mi < 4; ++mi) {
    int rbase = wrow + mi * 16 + quad * 4;
    float rs[4] = {0.f, 0.f, 0.f, 0.f};
    #pragma unroll
    for (int ni = 0; ni < 4; ++ni) {
      int gcol = wcol + ni * 16 + c16;
      #pragma unroll
      for (int t = 0; t < 4; ++t) {
        int grow = rbase + t;
        float sim = acc[mi][ni][t];
        float e = __expf(2.0f * sim);               // exp(sim / T), T=0.5
        if (diagBlk && gcol == grow) e = 0.0f;      // mask diagonal
        rs[t] += e;
        colsum[ni] += e;
        if (posBlk && gcol == grow + PN) {          // positive pair (and mirror)
          pos[grow] = sim;
          pos[grow + PN] = sim;
        }
      }
    }
    #pragma unroll
    for (int t = 0; t < 4; ++t) {
      #pragma unroll
      for (int off = 1; off <= 8; off <<= 1) rs[t] += __shfl_xor(rs[t], off, 64);
    }
    if (c16 == 0) {
      #pragma unroll
      for (int t = 0; t < 4; ++t) atomicAdd(&rowsum[rbase + t], rs[t]);
    }
  }
  if (!diagBlk) {   // column contributions = mirrored rows (symmetry)
    #pragma unroll
    for (int ni = 0; ni < 4; ++ni) {
      float cs = colsum[ni];
      cs += __shfl_xor(cs, 16, 64);
      cs += __shfl_xor(cs, 32, 64);
      if (quad == 0) atomicAdd(&rowsum[wcol + ni * 16 + c16], cs);
    }
  }
}

// ---------------------------------------------------------------------------
// Kernel 3: loss_i = log(denom_i) - 2*pos_i ; out = sum(w*loss)/sum(w)
// ---------------------------------------------------------------------------
__global__ __launch_bounds__(1024) void finalize_kernel(
    const float* __restrict__ rowsum, const float* __restrict__ pos,
    const float* __restrict__ w, float* __restrict__ out) {
  int tid = threadIdx.x;
  float wl = 0.f, ws = 0.f;
  for (int i = tid; i < PN2; i += 1024) {
    float li = logf(rowsum[i]) - 2.0f * pos[i];
    float wi = w[i & (PN - 1)];
    wl += wi * li;
    ws += wi;
  }
  #pragma unroll
  for (int off = 32; off >= 1; off >>= 1) {
    wl += __shfl_xor(wl, off, 64);
    ws += __shfl_xor(ws, off, 64);
  }
  __shared__ float pl[16], pw[16];
  if ((tid & 63) == 0) { pl[tid >> 6] = wl; pw[tid >> 6] = ws; }
  __syncthreads();
  if (tid == 0) {
    float sl = 0.f, sw = 0.f;
    #pragma unroll
    for (int k = 0; k < 16; ++k) { sl += pl[k]; sw += pw[k]; }
    out[0] = sl / sw;
  }
}

// ---------------------------------------------------------------------------
extern "C" void kernel_launch(void* const* d_in, const int* in_sizes, int n_in,
                              void* d_out, int out_size, void* d_ws, size_t ws_size,
                              hipStream_t stream) {
  const float* zi = (const float*)d_in[0];
  const float* zj = (const float*)d_in[1];
  const float* w  = (const float*)d_in[2];
  float* out = (float*)d_out;

  // Workspace: zn_perm bf16 [8192*256] = 4 MiB, then rowsum f32[8192], pos f32[8192]
  __hip_bfloat16* zn = (__hip_bfloat16*)d_ws;
  float* rowsum = (float*)((char*)d_ws + (size_t)PN2 * PD * 2);
  float* pos = rowsum + PN2;

  normalize_kernel<<<PN2, 256, 0, stream>>>(zi, zj, zn, rowsum);
  simsum_kernel<<<NTRI, 256, 0, stream>>>(zn, rowsum, pos);
  finalize_kernel<<<1, 1024, 0, stream>>>(rowsum, pos, w, out);
}